// Round 1
// baseline (3081.796 us; speedup 1.0000x reference)
//
#include <hip/hip_runtime.h>
#include <math.h>

#define N_NODES 100000
#define N_EDGES 1600000
#define HID 128
#define BN_EPS 1e-5f

// ws layout (floats): acc/h2 [0, N*H), sums at N*H: colsum[128], colsumsq[128], scale[128], shift[128]

// K1: gate = s0*x0 + s1*x1 ; acc = gate ; zero the sums area
__global__ __launch_bounds__(256) void k_gate(const float* __restrict__ x0,
                                              const float* __restrict__ x1,
                                              const float* __restrict__ mw,
                                              float* __restrict__ gate,
                                              float* __restrict__ acc,
                                              float* __restrict__ sums) {
    if (blockIdx.x == 0 && threadIdx.x < 256) sums[threadIdx.x] = 0.0f;
    int t = blockIdx.x * 256 + threadIdx.x;            // float4 index, exact grid
    float s0 = 1.0f / (1.0f + expf(-mw[0]));
    float s1 = 1.0f / (1.0f + expf(-mw[1]));
    float4 a = ((const float4*)x0)[t];
    float4 b = ((const float4*)x1)[t];
    float4 g;
    g.x = s0 * a.x + s1 * b.x;
    g.y = s0 * a.y + s1 * b.y;
    g.z = s0 * a.z + s1 * b.z;
    g.w = s0 * a.w + s1 * b.w;
    ((float4*)gate)[t] = g;
    ((float4*)acc)[t]  = g;
}

// K2: scatter-add. thread t -> edge e = t/32, channel group part = t%32 (4 floats)
__global__ __launch_bounds__(256) void k_scatter(const int* __restrict__ ei,
                                                 const float* __restrict__ gate,
                                                 float* __restrict__ acc) {
    int t = blockIdx.x * 256 + threadIdx.x;            // exact: N_EDGES*32 threads
    int e = t >> 5;
    int part = t & 31;
    int src = ei[e];
    int dst = ei[N_EDGES + e];
    float4 g = ((const float4*)(gate + (size_t)src * HID))[part];
    float* d = acc + (size_t)dst * HID + part * 4;
    atomicAdd(d + 0, g.x);
    atomicAdd(d + 1, g.y);
    atomicAdd(d + 2, g.z);
    atomicAdd(d + 3, g.w);
}

// K3: per-row MLP, in-place acc -> h2, accumulate column sums/sumsq
__global__ __launch_bounds__(512) void k_mlp(float* __restrict__ acc,
                                             const float* __restrict__ W1,
                                             const float* __restrict__ b1,
                                             const float* __restrict__ W2,
                                             const float* __restrict__ b2,
                                             float* __restrict__ sums) {
    __shared__ float w1[HID * HID];
    __shared__ float w2[HID * HID];
    __shared__ float rowbuf[8][HID];

    for (int i = threadIdx.x; i < HID * HID / 4; i += 512) {
        ((float4*)w1)[i] = ((const float4*)W1)[i];
        ((float4*)w2)[i] = ((const float4*)W2)[i];
    }
    __syncthreads();

    const int wave = threadIdx.x >> 6;
    const int lane = threadIdx.x & 63;
    const int waves_per_iter = gridDim.x * 8;
    const int iters = (N_NODES + waves_per_iter - 1) / waves_per_iter;

    float bias1a = b1[lane], bias1b = b1[lane + 64];
    float bias2a = b2[lane], bias2b = b2[lane + 64];

    float psum0 = 0.f, psum1 = 0.f, psq0 = 0.f, psq1 = 0.f;

    for (int it = 0; it < iters; ++it) {
        int row = (it * gridDim.x + blockIdx.x) * 8 + wave;
        bool ok = row < N_NODES;
        float* rp = acc + (size_t)row * HID;
        if (ok) {
            rowbuf[wave][lane]      = rp[lane];
            rowbuf[wave][lane + 64] = rp[lane + 64];
        }
        __syncthreads();
        float t0 = bias1a, t1 = bias1b;
        if (ok) {
#pragma unroll 8
            for (int k = 0; k < HID; ++k) {
                float rv = rowbuf[wave][k];
                t0 += rv * w1[k * HID + lane];
                t1 += rv * w1[k * HID + lane + 64];
            }
        }
        t0 = fmaxf(t0, 0.f);
        t1 = fmaxf(t1, 0.f);
        __syncthreads();
        if (ok) {
            rowbuf[wave][lane]      = t0;
            rowbuf[wave][lane + 64] = t1;
        }
        __syncthreads();
        if (ok) {
            float o0 = bias2a, o1 = bias2b;
#pragma unroll 8
            for (int k = 0; k < HID; ++k) {
                float tv = rowbuf[wave][k];
                o0 += tv * w2[k * HID + lane];
                o1 += tv * w2[k * HID + lane + 64];
            }
            rp[lane]      = o0;
            rp[lane + 64] = o1;
            psum0 += o0; psum1 += o1;
            psq0 += o0 * o0; psq1 += o1 * o1;
        }
        __syncthreads();
    }
    atomicAdd(&sums[lane],        psum0);
    atomicAdd(&sums[lane + 64],   psum1);
    atomicAdd(&sums[128 + lane],      psq0);
    atomicAdd(&sums[128 + lane + 64], psq1);
}

// K4: finalize BN scale/shift (one block, 128 threads)
__global__ void k_finalize(const float* __restrict__ sums,
                           const float* __restrict__ gamma,
                           const float* __restrict__ beta,
                           float* __restrict__ sc) {
    int c = threadIdx.x;
    float mean = sums[c] * (1.0f / N_NODES);
    float var  = sums[128 + c] * (1.0f / N_NODES) - mean * mean;
    float r = rsqrtf(var + BN_EPS);
    float scale = gamma[c] * r;
    sc[c]       = scale;
    sc[128 + c] = beta[c] - mean * scale;
}

// K5: apply BN: out = h2*scale + shift
__global__ __launch_bounds__(256) void k_bn(const float* __restrict__ h2,
                                            const float* __restrict__ sc,
                                            float* __restrict__ out) {
    int t = blockIdx.x * 256 + threadIdx.x;            // float4 index
    int c4 = t & 31;
    float4 scale = ((const float4*)sc)[c4];
    float4 shift = ((const float4*)sc)[32 + c4];
    float4 h = ((const float4*)h2)[t];
    float4 o;
    o.x = h.x * scale.x + shift.x;
    o.y = h.y * scale.y + shift.y;
    o.z = h.z * scale.z + shift.z;
    o.w = h.w * scale.w + shift.w;
    ((float4*)out)[t] = o;
}

extern "C" void kernel_launch(void* const* d_in, const int* in_sizes, int n_in,
                              void* d_out, int out_size, void* d_ws, size_t ws_size,
                              hipStream_t stream) {
    const float* x0 = (const float*)d_in[0];
    const float* x1 = (const float*)d_in[1];
    const int*   ei = (const int*)d_in[2];
    const float* mw = (const float*)d_in[3];
    const float* W1 = (const float*)d_in[4];
    const float* b1 = (const float*)d_in[5];
    const float* W2 = (const float*)d_in[6];
    const float* b2 = (const float*)d_in[7];
    const float* gamma = (const float*)d_in[8];
    const float* beta  = (const float*)d_in[9];

    float* out  = (float*)d_out;
    float* acc  = (float*)d_ws;                       // N*H floats (becomes h2)
    float* sums = acc + (size_t)N_NODES * HID;        // 512 floats
    float* sc   = sums + 256;                         // scale[128], shift[128]

    // K1: gate into d_out (scratch), acc init, zero sums
    {
        int nthread4 = N_NODES * HID / 4;             // 3,200,000
        k_gate<<<nthread4 / 256, 256, 0, stream>>>(x0, x1, mw, out, acc, sums);
    }
    // K2: scatter-add
    {
        long long total = (long long)N_EDGES * 32;    // 51,200,000
        k_scatter<<<(int)(total / 256), 256, 0, stream>>>(ei, out, acc);
    }
    // K3: MLP in-place + column sums
    k_mlp<<<256, 512, 0, stream>>>(acc, W1, b1, W2, b2, sums);
    // K4: finalize
    k_finalize<<<1, 128, 0, stream>>>(sums, gamma, beta, sc);
    // K5: BN apply
    {
        int nthread4 = N_NODES * HID / 4;
        k_bn<<<nthread4 / 256, 256, 0, stream>>>(acc, sc, out);
    }
}

// Round 2
// 696.160 us; speedup vs baseline: 4.4269x; 4.4269x over previous
//
#include <hip/hip_runtime.h>
#include <math.h>

#define N_NODES 100000
#define N_EDGES 1600000
#define HID 128
#define BN_EPS 1e-5f
#define SCAN_BLOCK 1024
#define NCHUNK ((N_NODES + SCAN_BLOCK - 1) / SCAN_BLOCK)   // 98

// ws layout (4B units):
//   float acc   [12,800,000]
//   float sums  [512]   (colsum[128], colsumsq[128])
//   float sc    [256]   (scale[128], shift[128])
//   int   offs  [100,001]
//   int   cursor[100,000]
//   int   part  [256]
//   int   srclist[1,600,000]

// K1: gate = s0*x0 + s1*x1 (into d_out as scratch); zero sums
__global__ __launch_bounds__(256) void k_gate(const float* __restrict__ x0,
                                              const float* __restrict__ x1,
                                              const float* __restrict__ mw,
                                              float* __restrict__ gate,
                                              float* __restrict__ sums) {
    if (blockIdx.x == 0 && threadIdx.x < 256) sums[threadIdx.x] = 0.0f;
    int t = blockIdx.x * 256 + threadIdx.x;            // float4 index, exact grid
    float s0 = 1.0f / (1.0f + expf(-mw[0]));
    float s1 = 1.0f / (1.0f + expf(-mw[1]));
    float4 a = ((const float4*)x0)[t];
    float4 b = ((const float4*)x1)[t];
    float4 g;
    g.x = s0 * a.x + s1 * b.x;
    g.y = s0 * a.y + s1 * b.y;
    g.z = s0 * a.z + s1 * b.z;
    g.w = s0 * a.w + s1 * b.w;
    ((float4*)gate)[t] = g;
}

// zero the per-node counters
__global__ __launch_bounds__(256) void k_zero(int* __restrict__ cnt) {
    int i = blockIdx.x * 256 + threadIdx.x;
    if (i < N_NODES) cnt[i] = 0;
}

// count in-degree per dst
__global__ __launch_bounds__(256) void k_count(const int* __restrict__ ei,
                                               int* __restrict__ cnt) {
    int e = blockIdx.x * 256 + threadIdx.x;            // exact: N_EDGES threads
    int dst = ei[N_EDGES + e];
    atomicAdd(&cnt[dst], 1);
}

// scan stage 1: per-1024 chunk exclusive scan; chunk totals to part[]
__global__ __launch_bounds__(SCAN_BLOCK) void k_scan1(const int* __restrict__ cnt,
                                                      int* __restrict__ offs,
                                                      int* __restrict__ part) {
    __shared__ int buf[SCAN_BLOCK];
    int i = blockIdx.x * SCAN_BLOCK + threadIdx.x;
    int v = (i < N_NODES) ? cnt[i] : 0;
    buf[threadIdx.x] = v;
    __syncthreads();
    for (int d = 1; d < SCAN_BLOCK; d <<= 1) {
        int t = (threadIdx.x >= d) ? buf[threadIdx.x - d] : 0;
        __syncthreads();
        buf[threadIdx.x] += t;
        __syncthreads();
    }
    if (i < N_NODES) offs[i] = buf[threadIdx.x] - v;   // exclusive within chunk
    if (threadIdx.x == SCAN_BLOCK - 1) part[blockIdx.x] = buf[SCAN_BLOCK - 1];
}

// scan stage 2: serial exclusive scan of the 98 partials (single thread; trivial)
__global__ void k_scan2(int* __restrict__ part, int* __restrict__ offs) {
    if (threadIdx.x == 0) {
        int run = 0;
        for (int i = 0; i < NCHUNK; ++i) { int v = part[i]; part[i] = run; run += v; }
        offs[N_NODES] = N_EDGES;
    }
}

// scan stage 3: add chunk base; init cursor
__global__ __launch_bounds__(SCAN_BLOCK) void k_scan3(int* __restrict__ offs,
                                                      const int* __restrict__ part,
                                                      int* __restrict__ cursor) {
    int i = blockIdx.x * SCAN_BLOCK + threadIdx.x;
    if (i < N_NODES) {
        int o = offs[i] + part[blockIdx.x];
        offs[i] = o;
        cursor[i] = o;
    }
}

// fill: srclist bucketed by dst (order within bucket irrelevant — sum commutes)
__global__ __launch_bounds__(256) void k_fill(const int* __restrict__ ei,
                                              int* __restrict__ cursor,
                                              int* __restrict__ srclist) {
    int e = blockIdx.x * 256 + threadIdx.x;            // exact: N_EDGES threads
    int src = ei[e];
    int dst = ei[N_EDGES + e];
    int pos = atomicAdd(&cursor[dst], 1);
    srclist[pos] = src;
}

// gather-sum: h = gate[node] + sum_{src in N(node)} gate[src]
__global__ __launch_bounds__(128) void k_agg(const float* __restrict__ gate,
                                             const int* __restrict__ offs,
                                             const int* __restrict__ srclist,
                                             float* __restrict__ acc) {
    int node = blockIdx.x;
    int c = threadIdx.x;
    int start = offs[node], end = offs[node + 1];
    float sum = gate[(size_t)node * HID + c];
    __shared__ int s_src[128];
    for (int base = start; base < end; base += 128) {
        int n = end - base; if (n > 128) n = 128;
        if (c < n) s_src[c] = srclist[base + c];
        __syncthreads();
        for (int j = 0; j < n; ++j)
            sum += gate[(size_t)s_src[j] * HID + c];
        __syncthreads();
    }
    acc[(size_t)node * HID + c] = sum;
}

// fallback scatter (atomics) if ws is too small for CSR
__global__ __launch_bounds__(256) void k_scatter(const int* __restrict__ ei,
                                                 const float* __restrict__ gate,
                                                 float* __restrict__ acc) {
    int t = blockIdx.x * 256 + threadIdx.x;
    int e = t >> 5;
    int part = t & 31;
    int src = ei[e];
    int dst = ei[N_EDGES + e];
    float4 g = ((const float4*)(gate + (size_t)src * HID))[part];
    float* d = acc + (size_t)dst * HID + part * 4;
    atomicAdd(d + 0, g.x);
    atomicAdd(d + 1, g.y);
    atomicAdd(d + 2, g.z);
    atomicAdd(d + 3, g.w);
}

// K3: per-row MLP, in-place acc -> h2, accumulate column sums/sumsq
__global__ __launch_bounds__(512) void k_mlp(float* __restrict__ acc,
                                             const float* __restrict__ W1,
                                             const float* __restrict__ b1,
                                             const float* __restrict__ W2,
                                             const float* __restrict__ b2,
                                             float* __restrict__ sums) {
    __shared__ float w1[HID * HID];
    __shared__ float w2[HID * HID];
    __shared__ float rowbuf[8][HID];

    for (int i = threadIdx.x; i < HID * HID / 4; i += 512) {
        ((float4*)w1)[i] = ((const float4*)W1)[i];
        ((float4*)w2)[i] = ((const float4*)W2)[i];
    }
    __syncthreads();

    const int wave = threadIdx.x >> 6;
    const int lane = threadIdx.x & 63;
    const int waves_per_iter = gridDim.x * 8;
    const int iters = (N_NODES + waves_per_iter - 1) / waves_per_iter;

    float bias1a = b1[lane], bias1b = b1[lane + 64];
    float bias2a = b2[lane], bias2b = b2[lane + 64];

    float psum0 = 0.f, psum1 = 0.f, psq0 = 0.f, psq1 = 0.f;

    for (int it = 0; it < iters; ++it) {
        int row = (it * gridDim.x + blockIdx.x) * 8 + wave;
        bool ok = row < N_NODES;
        float* rp = acc + (size_t)row * HID;
        if (ok) {
            rowbuf[wave][lane]      = rp[lane];
            rowbuf[wave][lane + 64] = rp[lane + 64];
        }
        __syncthreads();
        float t0 = bias1a, t1 = bias1b;
        if (ok) {
#pragma unroll 8
            for (int k = 0; k < HID; ++k) {
                float rv = rowbuf[wave][k];
                t0 += rv * w1[k * HID + lane];
                t1 += rv * w1[k * HID + lane + 64];
            }
        }
        t0 = fmaxf(t0, 0.f);
        t1 = fmaxf(t1, 0.f);
        __syncthreads();
        if (ok) {
            rowbuf[wave][lane]      = t0;
            rowbuf[wave][lane + 64] = t1;
        }
        __syncthreads();
        if (ok) {
            float o0 = bias2a, o1 = bias2b;
#pragma unroll 8
            for (int k = 0; k < HID; ++k) {
                float tv = rowbuf[wave][k];
                o0 += tv * w2[k * HID + lane];
                o1 += tv * w2[k * HID + lane + 64];
            }
            rp[lane]      = o0;
            rp[lane + 64] = o1;
            psum0 += o0; psum1 += o1;
            psq0 += o0 * o0; psq1 += o1 * o1;
        }
        __syncthreads();
    }
    atomicAdd(&sums[lane],        psum0);
    atomicAdd(&sums[lane + 64],   psum1);
    atomicAdd(&sums[128 + lane],      psq0);
    atomicAdd(&sums[128 + lane + 64], psq1);
}

// K4: finalize BN scale/shift
__global__ void k_finalize(const float* __restrict__ sums,
                           const float* __restrict__ gamma,
                           const float* __restrict__ beta,
                           float* __restrict__ sc) {
    int c = threadIdx.x;
    float mean = sums[c] * (1.0f / N_NODES);
    float var  = sums[128 + c] * (1.0f / N_NODES) - mean * mean;
    float r = rsqrtf(var + BN_EPS);
    float scale = gamma[c] * r;
    sc[c]       = scale;
    sc[128 + c] = beta[c] - mean * scale;
}

// K5: out = h2*scale + shift
__global__ __launch_bounds__(256) void k_bn(const float* __restrict__ h2,
                                            const float* __restrict__ sc,
                                            float* __restrict__ out) {
    int t = blockIdx.x * 256 + threadIdx.x;
    int c4 = t & 31;
    float4 scale = ((const float4*)sc)[c4];
    float4 shift = ((const float4*)sc)[32 + c4];
    float4 h = ((const float4*)h2)[t];
    float4 o;
    o.x = h.x * scale.x + shift.x;
    o.y = h.y * scale.y + shift.y;
    o.z = h.z * scale.z + shift.z;
    o.w = h.w * scale.w + shift.w;
    ((float4*)out)[t] = o;
}

extern "C" void kernel_launch(void* const* d_in, const int* in_sizes, int n_in,
                              void* d_out, int out_size, void* d_ws, size_t ws_size,
                              hipStream_t stream) {
    const float* x0 = (const float*)d_in[0];
    const float* x1 = (const float*)d_in[1];
    const int*   ei = (const int*)d_in[2];
    const float* mw = (const float*)d_in[3];
    const float* W1 = (const float*)d_in[4];
    const float* b1 = (const float*)d_in[5];
    const float* W2 = (const float*)d_in[6];
    const float* b2 = (const float*)d_in[7];
    const float* gamma = (const float*)d_in[8];
    const float* beta  = (const float*)d_in[9];

    float* out  = (float*)d_out;
    float* acc  = (float*)d_ws;                               // 12.8M floats (h, then h2)
    float* sums = acc + (size_t)N_NODES * HID;                // 512
    float* sc   = sums + 512;                                 // 256
    int* offs    = (int*)(sc + 256);                          // 100,001
    int* cursor  = offs + (N_NODES + 1);                      // 100,000
    int* part    = cursor + N_NODES;                          // 256
    int* srclist = part + 256;                                // 1,600,000

    size_t needed = ((size_t)(srclist + N_EDGES) - (size_t)d_ws);

    int nthread4 = N_NODES * HID / 4;                         // 3,200,000
    k_gate<<<nthread4 / 256, 256, 0, stream>>>(x0, x1, mw, out, sums);

    if (ws_size >= needed) {
        // CSR build + gather
        k_zero<<<(N_NODES + 255) / 256, 256, 0, stream>>>(cursor);   // cursor used as cnt
        k_count<<<N_EDGES / 256, 256, 0, stream>>>(ei, cursor);
        k_scan1<<<NCHUNK, SCAN_BLOCK, 0, stream>>>(cursor, offs, part);
        k_scan2<<<1, 64, 0, stream>>>(part, offs);
        k_scan3<<<NCHUNK, SCAN_BLOCK, 0, stream>>>(offs, part, cursor);
        k_fill<<<N_EDGES / 256, 256, 0, stream>>>(ei, cursor, srclist);
        k_agg<<<N_NODES, 128, 0, stream>>>(out, offs, srclist, acc);
    } else {
        // fallback: atomic scatter
        hipMemcpyAsync(acc, out, (size_t)N_NODES * HID * sizeof(float),
                       hipMemcpyDeviceToDevice, stream);
        long long total = (long long)N_EDGES * 32;
        k_scatter<<<(int)(total / 256), 256, 0, stream>>>(ei, out, acc);
    }

    k_mlp<<<256, 512, 0, stream>>>(acc, W1, b1, W2, b2, sums);
    k_finalize<<<1, 128, 0, stream>>>(sums, gamma, beta, sc);
    k_bn<<<nthread4 / 256, 256, 0, stream>>>(acc, sc, out);
}

// Round 3
// 392.354 us; speedup vs baseline: 7.8546x; 1.7743x over previous
//
#include <hip/hip_runtime.h>
#include <math.h>

#define N_NODES 100000
#define N_EDGES 1600000
#define HID 128
#define BN_EPS 1e-5f
#define SCAN_BLOCK 1024
#define NCHUNK ((N_NODES + SCAN_BLOCK - 1) / SCAN_BLOCK)   // 98
#define BM 64

typedef __attribute__((ext_vector_type(8))) short bf16x8;
typedef __attribute__((ext_vector_type(4))) float f32x4;

__device__ inline unsigned short f2bf(float f) {
    unsigned u = __float_as_uint(f);
    unsigned r = u + 0x7FFFu + ((u >> 16) & 1u);   // RNE
    return (unsigned short)(r >> 16);
}
__device__ inline unsigned pk2(float lo, float hi) {
    return (unsigned)f2bf(lo) | ((unsigned)f2bf(hi) << 16);
}

// K1: gate = s0*x0 + s1*x1 (into d_out as scratch); zero shadow sums
__global__ __launch_bounds__(256) void k_gate(const float* __restrict__ x0,
                                              const float* __restrict__ x1,
                                              const float* __restrict__ mw,
                                              float* __restrict__ gate,
                                              float* __restrict__ shadow) {
    if (blockIdx.x < 64) shadow[blockIdx.x * 256 + threadIdx.x] = 0.0f;
    int t = blockIdx.x * 256 + threadIdx.x;            // float4 index, exact grid
    float s0 = 1.0f / (1.0f + expf(-mw[0]));
    float s1 = 1.0f / (1.0f + expf(-mw[1]));
    float4 a = ((const float4*)x0)[t];
    float4 b = ((const float4*)x1)[t];
    float4 g;
    g.x = s0 * a.x + s1 * b.x;
    g.y = s0 * a.y + s1 * b.y;
    g.z = s0 * a.z + s1 * b.z;
    g.w = s0 * a.w + s1 * b.w;
    ((float4*)gate)[t] = g;
}

// one-time: W1,W2 fp32 [k][n] -> bf16 transposed [n][k]
__global__ __launch_bounds__(256) void k_prep(const float* __restrict__ W1,
                                              const float* __restrict__ W2,
                                              unsigned short* __restrict__ W1T,
                                              unsigned short* __restrict__ W2T) {
    int t = blockIdx.x * 256 + threadIdx.x;            // 16384 threads
    int k = t >> 7, n = t & 127;
    W1T[n * HID + k] = f2bf(W1[t]);
    W2T[n * HID + k] = f2bf(W2[t]);
}

__global__ __launch_bounds__(256) void k_zero(int* __restrict__ cnt) {
    int i = blockIdx.x * 256 + threadIdx.x;
    if (i < N_NODES) cnt[i] = 0;
}

__global__ __launch_bounds__(256) void k_count(const int* __restrict__ ei,
                                               int* __restrict__ cnt) {
    int e = blockIdx.x * 256 + threadIdx.x;
    int dst = ei[N_EDGES + e];
    atomicAdd(&cnt[dst], 1);
}

__global__ __launch_bounds__(SCAN_BLOCK) void k_scan1(const int* __restrict__ cnt,
                                                      int* __restrict__ offs,
                                                      int* __restrict__ part) {
    __shared__ int buf[SCAN_BLOCK];
    int i = blockIdx.x * SCAN_BLOCK + threadIdx.x;
    int v = (i < N_NODES) ? cnt[i] : 0;
    buf[threadIdx.x] = v;
    __syncthreads();
    for (int d = 1; d < SCAN_BLOCK; d <<= 1) {
        int t = (threadIdx.x >= d) ? buf[threadIdx.x - d] : 0;
        __syncthreads();
        buf[threadIdx.x] += t;
        __syncthreads();
    }
    if (i < N_NODES) offs[i] = buf[threadIdx.x] - v;
    if (threadIdx.x == SCAN_BLOCK - 1) part[blockIdx.x] = buf[SCAN_BLOCK - 1];
}

__global__ void k_scan2(int* __restrict__ part, int* __restrict__ offs) {
    if (threadIdx.x == 0) {
        int run = 0;
        for (int i = 0; i < NCHUNK; ++i) { int v = part[i]; part[i] = run; run += v; }
        offs[N_NODES] = N_EDGES;
    }
}

__global__ __launch_bounds__(SCAN_BLOCK) void k_scan3(int* __restrict__ offs,
                                                      const int* __restrict__ part,
                                                      int* __restrict__ cursor) {
    int i = blockIdx.x * SCAN_BLOCK + threadIdx.x;
    if (i < N_NODES) {
        int o = offs[i] + part[blockIdx.x];
        offs[i] = o;
        cursor[i] = o;
    }
}

__global__ __launch_bounds__(256) void k_fill(const int* __restrict__ ei,
                                              int* __restrict__ cursor,
                                              int* __restrict__ srclist) {
    int e = blockIdx.x * 256 + threadIdx.x;
    int src = ei[e];
    int dst = ei[N_EDGES + e];
    int pos = atomicAdd(&cursor[dst], 1);
    srclist[pos] = src;
}

__global__ __launch_bounds__(128) void k_agg(const float* __restrict__ gate,
                                             const int* __restrict__ offs,
                                             const int* __restrict__ srclist,
                                             float* __restrict__ acc) {
    int node = blockIdx.x;
    int c = threadIdx.x;
    int start = offs[node], end = offs[node + 1];
    float sum = gate[(size_t)node * HID + c];
    __shared__ int s_src[128];
    for (int base = start; base < end; base += 128) {
        int n = end - base; if (n > 128) n = 128;
        if (c < n) s_src[c] = srclist[base + c];
        __syncthreads();
        for (int j = 0; j < n; ++j)
            sum += gate[(size_t)s_src[j] * HID + c];
        __syncthreads();
    }
    acc[(size_t)node * HID + c] = sum;
}

// fallback scatter (atomics) if ws is too small for CSR
__global__ __launch_bounds__(256) void k_scatter(const int* __restrict__ ei,
                                                 const float* __restrict__ gate,
                                                 float* __restrict__ acc) {
    int t = blockIdx.x * 256 + threadIdx.x;
    int e = t >> 5;
    int part = t & 31;
    int src = ei[e];
    int dst = ei[N_EDGES + e];
    float4 g = ((const float4*)(gate + (size_t)src * HID))[part];
    float* d = acc + (size_t)dst * HID + part * 4;
    atomicAdd(d + 0, g.x);
    atomicAdd(d + 1, g.y);
    atomicAdd(d + 2, g.z);
    atomicAdd(d + 3, g.w);
}

// MFMA MLP: 64-row tile, 4 waves (2x2), wave tile 32x64, K=128 in 4 chunks.
// h2 written in-place over hbuf; per-column sums into shadow[64][256].
__global__ __launch_bounds__(256, 2) void k_mlp(float* __restrict__ hbuf,
                                                const unsigned short* __restrict__ W1T,
                                                const unsigned short* __restrict__ W2T,
                                                const float* __restrict__ b1,
                                                const float* __restrict__ b2,
                                                float* __restrict__ shadow) {
    __shared__ short lds_x[BM * HID];        // 16KB: X, then X2, then colsums
    __shared__ short lds_w1[HID * HID];      // 32KB
    __shared__ short lds_w2[HID * HID];      // 32KB

    const int tid = threadIdx.x;
    const int bid = blockIdx.x;
    const int m0 = bid * BM;

    // stage weights (bf16 W^T [n][k]) with XOR swizzle on 16B chunks
    for (int c = tid; c < 2048; c += 256) {
        int n = c >> 4, k16 = c & 15;
        int4 v1 = ((const int4*)W1T)[c];
        int4 v2 = ((const int4*)W2T)[c];
        int boff = n * 256 + ((k16 * 16) ^ ((n & 7) << 4));
        *(int4*)((char*)lds_w1 + boff) = v1;
        *(int4*)((char*)lds_w2 + boff) = v2;
    }
    // stage X rows fp32 -> bf16
    for (int c = tid; c < BM * 16; c += 256) {
        int r = c >> 4, k16 = c & 15;
        int row = m0 + r;
        unsigned pk[4] = {0u, 0u, 0u, 0u};
        if (row < N_NODES) {
            const float4* p = (const float4*)(hbuf + (size_t)row * HID + k16 * 8);
            float4 aa = p[0], bb = p[1];
            pk[0] = pk2(aa.x, aa.y); pk[1] = pk2(aa.z, aa.w);
            pk[2] = pk2(bb.x, bb.y); pk[3] = pk2(bb.z, bb.w);
        }
        int boff = r * 256 + ((k16 * 16) ^ ((r & 7) << 4));
        *(int4*)((char*)lds_x + boff) = *(int4*)pk;
    }

    const int wid = tid >> 6, lane = tid & 63;
    const int wrow = wid >> 1, wcol = wid & 1;
    const int l15 = lane & 15, l4 = lane >> 4;

    float b1g[4], b2g[4];
#pragma unroll
    for (int nf = 0; nf < 4; ++nf) {
        int n = wcol * 64 + nf * 16 + l15;
        b1g[nf] = b1[n];
        b2g[nf] = b2[n];
    }

    __syncthreads();

    // GEMM1: Y = X @ W1
    f32x4 acc1[2][4];
#pragma unroll
    for (int mf = 0; mf < 2; ++mf)
#pragma unroll
        for (int nf = 0; nf < 4; ++nf) acc1[mf][nf] = (f32x4){0.f, 0.f, 0.f, 0.f};

#pragma unroll
    for (int kc = 0; kc < 4; ++kc) {
        bf16x8 av[2], bv[4];
#pragma unroll
        for (int mf = 0; mf < 2; ++mf) {
            int r = wrow * 32 + mf * 16 + l15;
            int boff = r * 256 + (((kc * 64) + l4 * 16) ^ ((r & 7) << 4));
            av[mf] = *(const bf16x8*)((const char*)lds_x + boff);
        }
#pragma unroll
        for (int nf = 0; nf < 4; ++nf) {
            int n = wcol * 64 + nf * 16 + l15;
            int boff = n * 256 + (((kc * 64) + l4 * 16) ^ ((n & 7) << 4));
            bv[nf] = *(const bf16x8*)((const char*)lds_w1 + boff);
        }
#pragma unroll
        for (int mf = 0; mf < 2; ++mf)
#pragma unroll
            for (int nf = 0; nf < 4; ++nf)
                acc1[mf][nf] = __builtin_amdgcn_mfma_f32_16x16x32_bf16(av[mf], bv[nf], acc1[mf][nf], 0, 0, 0);
    }

    __syncthreads();

    // bias1 + ReLU -> X2 (bf16, swizzled) into lds_x
#pragma unroll
    for (int mf = 0; mf < 2; ++mf)
#pragma unroll
        for (int nf = 0; nf < 4; ++nf) {
            int n = wcol * 64 + nf * 16 + l15;
#pragma unroll
            for (int r = 0; r < 4; ++r) {
                int row = wrow * 32 + mf * 16 + l4 * 4 + r;
                float v = fmaxf(acc1[mf][nf][r] + b1g[nf], 0.f);
                int boff = row * 256 + ((2 * n) ^ ((row & 7) << 4));
                *(unsigned short*)((char*)lds_x + boff) = f2bf(v);
            }
        }

    __syncthreads();

    // GEMM2: h2 = X2 @ W2
    f32x4 acc2[2][4];
#pragma unroll
    for (int mf = 0; mf < 2; ++mf)
#pragma unroll
        for (int nf = 0; nf < 4; ++nf) acc2[mf][nf] = (f32x4){0.f, 0.f, 0.f, 0.f};

#pragma unroll
    for (int kc = 0; kc < 4; ++kc) {
        bf16x8 av[2], bv[4];
#pragma unroll
        for (int mf = 0; mf < 2; ++mf) {
            int r = wrow * 32 + mf * 16 + l15;
            int boff = r * 256 + (((kc * 64) + l4 * 16) ^ ((r & 7) << 4));
            av[mf] = *(const bf16x8*)((const char*)lds_x + boff);
        }
#pragma unroll
        for (int nf = 0; nf < 4; ++nf) {
            int n = wcol * 64 + nf * 16 + l15;
            int boff = n * 256 + (((kc * 64) + l4 * 16) ^ ((n & 7) << 4));
            bv[nf] = *(const bf16x8*)((const char*)lds_w2 + boff);
        }
#pragma unroll
        for (int mf = 0; mf < 2; ++mf)
#pragma unroll
            for (int nf = 0; nf < 4; ++nf)
                acc2[mf][nf] = __builtin_amdgcn_mfma_f32_16x16x32_bf16(av[mf], bv[nf], acc2[mf][nf], 0, 0, 0);
    }

    __syncthreads();
    float* cs = (float*)lds_x;
    cs[tid] = 0.f;     // [0..127]=colsum, [128..255]=colsumsq
    __syncthreads();

    // epilogue: bias2, store h2 (in place), column partials
    float psum[4] = {0.f, 0.f, 0.f, 0.f}, psq[4] = {0.f, 0.f, 0.f, 0.f};
#pragma unroll
    for (int mf = 0; mf < 2; ++mf)
#pragma unroll
        for (int nf = 0; nf < 4; ++nf) {
            int n = wcol * 64 + nf * 16 + l15;
#pragma unroll
            for (int r = 0; r < 4; ++r) {
                int row = m0 + wrow * 32 + mf * 16 + l4 * 4 + r;
                float v = acc2[mf][nf][r] + b2g[nf];
                if (row < N_NODES) {
                    hbuf[(size_t)row * HID + n] = v;
                    psum[nf] += v;
                    psq[nf] += v * v;
                }
            }
        }
#pragma unroll
    for (int nf = 0; nf < 4; ++nf) {
        float s = psum[nf], q = psq[nf];
        s += __shfl_xor(s, 16); q += __shfl_xor(q, 16);
        s += __shfl_xor(s, 32); q += __shfl_xor(q, 32);
        if (lane < 16) {
            int n = wcol * 64 + nf * 16 + lane;
            atomicAdd(&cs[n], s);
            atomicAdd(&cs[HID + n], q);
        }
    }
    __syncthreads();
    atomicAdd(&shadow[(bid & 63) * 256 + tid], cs[tid]);
}

// finalize BN scale/shift from shadow partials
__global__ void k_finalize(const float* __restrict__ shadow,
                           const float* __restrict__ gamma,
                           const float* __restrict__ beta,
                           float* __restrict__ sc) {
    int c = threadIdx.x;     // 0..127
    float sum = 0.f, sq = 0.f;
    for (int i = 0; i < 64; ++i) {
        sum += shadow[i * 256 + c];
        sq  += shadow[i * 256 + 128 + c];
    }
    float mean = sum * (1.0f / N_NODES);
    float var  = sq * (1.0f / N_NODES) - mean * mean;
    float r = rsqrtf(var + BN_EPS);
    float scale = gamma[c] * r;
    sc[c]       = scale;
    sc[128 + c] = beta[c] - mean * scale;
}

__global__ __launch_bounds__(256) void k_bn(const float* __restrict__ h2,
                                            const float* __restrict__ sc,
                                            float* __restrict__ out) {
    int t = blockIdx.x * 256 + threadIdx.x;
    int c4 = t & 31;
    float4 scale = ((const float4*)sc)[c4];
    float4 shift = ((const float4*)sc)[32 + c4];
    float4 h = ((const float4*)h2)[t];
    float4 o;
    o.x = h.x * scale.x + shift.x;
    o.y = h.y * scale.y + shift.y;
    o.z = h.z * scale.z + shift.z;
    o.w = h.w * scale.w + shift.w;
    ((float4*)out)[t] = o;
}

extern "C" void kernel_launch(void* const* d_in, const int* in_sizes, int n_in,
                              void* d_out, int out_size, void* d_ws, size_t ws_size,
                              hipStream_t stream) {
    const float* x0 = (const float*)d_in[0];
    const float* x1 = (const float*)d_in[1];
    const int*   ei = (const int*)d_in[2];
    const float* mw = (const float*)d_in[3];
    const float* W1 = (const float*)d_in[4];
    const float* b1 = (const float*)d_in[5];
    const float* W2 = (const float*)d_in[6];
    const float* b2 = (const float*)d_in[7];
    const float* gamma = (const float*)d_in[8];
    const float* beta  = (const float*)d_in[9];

    float* out    = (float*)d_out;
    float* acc    = (float*)d_ws;                         // 12.8M floats (h, then h2)
    float* shadow = acc + (size_t)N_NODES * HID;          // 16384
    float* sc     = shadow + 16384;                       // 256
    unsigned short* W1T = (unsigned short*)(sc + 256);    // 16384 u16
    unsigned short* W2T = W1T + 16384;                    // 16384 u16
    int* offs    = (int*)(W2T + 16384);                   // 100,001
    int* cursor  = offs + (N_NODES + 1);                  // 100,000
    int* part    = cursor + N_NODES;                      // 256
    int* srclist = part + 256;                            // 1,600,000

    size_t needed = (size_t)((char*)(srclist + N_EDGES) - (char*)d_ws);

    int nthread4 = N_NODES * HID / 4;                     // 3,200,000
    k_gate<<<nthread4 / 256, 256, 0, stream>>>(x0, x1, mw, out, shadow);
    k_prep<<<64, 256, 0, stream>>>(W1, W2, W1T, W2T);

    if (ws_size >= needed) {
        k_zero<<<(N_NODES + 255) / 256, 256, 0, stream>>>(cursor);
        k_count<<<N_EDGES / 256, 256, 0, stream>>>(ei, cursor);
        k_scan1<<<NCHUNK, SCAN_BLOCK, 0, stream>>>(cursor, offs, part);
        k_scan2<<<1, 64, 0, stream>>>(part, offs);
        k_scan3<<<NCHUNK, SCAN_BLOCK, 0, stream>>>(offs, part, cursor);
        k_fill<<<N_EDGES / 256, 256, 0, stream>>>(ei, cursor, srclist);
        k_agg<<<N_NODES, 128, 0, stream>>>(out, offs, srclist, acc);
    } else {
        hipMemcpyAsync(acc, out, (size_t)N_NODES * HID * sizeof(float),
                       hipMemcpyDeviceToDevice, stream);
        long long total = (long long)N_EDGES * 32;
        k_scatter<<<(int)(total / 256), 256, 0, stream>>>(ei, out, acc);
    }

    // MFMA MLP (in-place h -> h2) + column sums
    k_mlp<<<(N_NODES + BM - 1) / BM, 256, 0, stream>>>(acc, W1T, W2T, b1, b2, shadow);
    k_finalize<<<1, 128, 0, stream>>>(shadow, gamma, beta, sc);
    k_bn<<<nthread4 / 256, 256, 0, stream>>>(acc, sc, out);
}

// Round 4
// 338.408 us; speedup vs baseline: 9.1067x; 1.1594x over previous
//
#include <hip/hip_runtime.h>
#include <math.h>

#define N_NODES 100000
#define N_EDGES 1600000
#define HID 128
#define BN_EPS 1e-5f
#define BM 64

typedef __attribute__((ext_vector_type(8))) short bf16x8;
typedef __attribute__((ext_vector_type(4))) float f32x4;

__device__ inline unsigned short f2bf(float f) {
    unsigned u = __float_as_uint(f);
    unsigned r = u + 0x7FFFu + ((u >> 16) & 1u);   // RNE
    return (unsigned short)(r >> 16);
}
__device__ inline unsigned pk2(float lo, float hi) {
    return (unsigned)f2bf(lo) | ((unsigned)f2bf(hi) << 16);
}

// K1: gate = s0*x0 + s1*x1 (into d_out as scratch); zero shadow sums; head = -1
__global__ __launch_bounds__(256) void k_gate(const float* __restrict__ x0,
                                              const float* __restrict__ x1,
                                              const float* __restrict__ mw,
                                              float* __restrict__ gate,
                                              float* __restrict__ shadow,
                                              int* __restrict__ head) {
    int t = blockIdx.x * 256 + threadIdx.x;            // float4 index, exact grid
    if (blockIdx.x < 64) shadow[t] = 0.0f;
    if (t < N_NODES) head[t] = -1;
    float s0 = 1.0f / (1.0f + expf(-mw[0]));
    float s1 = 1.0f / (1.0f + expf(-mw[1]));
    float4 a = ((const float4*)x0)[t];
    float4 b = ((const float4*)x1)[t];
    float4 g;
    g.x = s0 * a.x + s1 * b.x;
    g.y = s0 * a.y + s1 * b.y;
    g.z = s0 * a.z + s1 * b.z;
    g.w = s0 * a.w + s1 * b.w;
    ((float4*)gate)[t] = g;
}

// one-time: W1,W2 fp32 [k][n] -> bf16 transposed [n][k]
__global__ __launch_bounds__(256) void k_prep(const float* __restrict__ W1,
                                              const float* __restrict__ W2,
                                              unsigned short* __restrict__ W1T,
                                              unsigned short* __restrict__ W2T) {
    int t = blockIdx.x * 256 + threadIdx.x;            // 16384 threads
    int k = t >> 7, n = t & 127;
    W1T[n * HID + k] = f2bf(W1[t]);
    W2T[n * HID + k] = f2bf(W2[t]);
}

// build per-dst linked list: nxt[e] = old head, head[dst] = e
__global__ __launch_bounds__(256) void k_build(const int* __restrict__ ei,
                                               int* __restrict__ head,
                                               int* __restrict__ nxt) {
    int e = blockIdx.x * 256 + threadIdx.x;            // exact: N_EDGES threads
    int dst = ei[N_EDGES + e];
    nxt[e] = atomicExch(&head[dst], e);
}

// gather-sum via list walk: one wave per node, float2 row loads
__global__ __launch_bounds__(256) void k_agg(const float* __restrict__ gate,
                                             const int* __restrict__ ei,
                                             const int* __restrict__ head,
                                             const int* __restrict__ nxt,
                                             float* __restrict__ acc) {
    int node = blockIdx.x * 4 + (threadIdx.x >> 6);    // exact: 25000 blocks
    int lane = threadIdx.x & 63;
    float2 sum = *(const float2*)(gate + (size_t)node * HID + lane * 2);
    int e = head[node];                                // uniform per wave (broadcast)
    while (e >= 0) {
        int src = ei[e];
        int nx  = nxt[e];
        float2 v = ((const float2*)(gate + (size_t)src * HID))[lane];
        sum.x += v.x;
        sum.y += v.y;
        e = nx;
    }
    *(float2*)(acc + (size_t)node * HID + lane * 2) = sum;
}

// fallback scatter (atomics) if ws is too small
__global__ __launch_bounds__(256) void k_scatter(const int* __restrict__ ei,
                                                 const float* __restrict__ gate,
                                                 float* __restrict__ acc) {
    int t = blockIdx.x * 256 + threadIdx.x;
    int e = t >> 5;
    int part = t & 31;
    int src = ei[e];
    int dst = ei[N_EDGES + e];
    float4 g = ((const float4*)(gate + (size_t)src * HID))[part];
    float* d = acc + (size_t)dst * HID + part * 4;
    atomicAdd(d + 0, g.x);
    atomicAdd(d + 1, g.y);
    atomicAdd(d + 2, g.z);
    atomicAdd(d + 3, g.w);
}

// MFMA MLP: 64-row tile, 4 waves (2x2), wave tile 32x64, K=128 in 4 chunks.
// h2 written in-place over hbuf; per-column sums into shadow[64][256].
__global__ __launch_bounds__(256, 2) void k_mlp(float* __restrict__ hbuf,
                                                const unsigned short* __restrict__ W1T,
                                                const unsigned short* __restrict__ W2T,
                                                const float* __restrict__ b1,
                                                const float* __restrict__ b2,
                                                float* __restrict__ shadow) {
    __shared__ short lds_x[BM * HID];        // 16KB: X, then X2, then colsums
    __shared__ short lds_w1[HID * HID];      // 32KB
    __shared__ short lds_w2[HID * HID];      // 32KB

    const int tid = threadIdx.x;
    const int bid = blockIdx.x;
    const int m0 = bid * BM;

    // stage weights (bf16 W^T [n][k]) with XOR swizzle on 16B chunks
    for (int c = tid; c < 2048; c += 256) {
        int n = c >> 4, k16 = c & 15;
        int4 v1 = ((const int4*)W1T)[c];
        int4 v2 = ((const int4*)W2T)[c];
        int boff = n * 256 + ((k16 * 16) ^ ((n & 7) << 4));
        *(int4*)((char*)lds_w1 + boff) = v1;
        *(int4*)((char*)lds_w2 + boff) = v2;
    }
    // stage X rows fp32 -> bf16
    for (int c = tid; c < BM * 16; c += 256) {
        int r = c >> 4, k16 = c & 15;
        int row = m0 + r;
        unsigned pk[4] = {0u, 0u, 0u, 0u};
        if (row < N_NODES) {
            const float4* p = (const float4*)(hbuf + (size_t)row * HID + k16 * 8);
            float4 aa = p[0], bb = p[1];
            pk[0] = pk2(aa.x, aa.y); pk[1] = pk2(aa.z, aa.w);
            pk[2] = pk2(bb.x, bb.y); pk[3] = pk2(bb.z, bb.w);
        }
        int boff = r * 256 + ((k16 * 16) ^ ((r & 7) << 4));
        *(int4*)((char*)lds_x + boff) = *(int4*)pk;
    }

    const int wid = tid >> 6, lane = tid & 63;
    const int wrow = wid >> 1, wcol = wid & 1;
    const int l15 = lane & 15, l4 = lane >> 4;

    float b1g[4], b2g[4];
#pragma unroll
    for (int nf = 0; nf < 4; ++nf) {
        int n = wcol * 64 + nf * 16 + l15;
        b1g[nf] = b1[n];
        b2g[nf] = b2[n];
    }

    __syncthreads();

    // GEMM1: Y = X @ W1
    f32x4 acc1[2][4];
#pragma unroll
    for (int mf = 0; mf < 2; ++mf)
#pragma unroll
        for (int nf = 0; nf < 4; ++nf) acc1[mf][nf] = (f32x4){0.f, 0.f, 0.f, 0.f};

#pragma unroll
    for (int kc = 0; kc < 4; ++kc) {
        bf16x8 av[2], bv[4];
#pragma unroll
        for (int mf = 0; mf < 2; ++mf) {
            int r = wrow * 32 + mf * 16 + l15;
            int boff = r * 256 + (((kc * 64) + l4 * 16) ^ ((r & 7) << 4));
            av[mf] = *(const bf16x8*)((const char*)lds_x + boff);
        }
#pragma unroll
        for (int nf = 0; nf < 4; ++nf) {
            int n = wcol * 64 + nf * 16 + l15;
            int boff = n * 256 + (((kc * 64) + l4 * 16) ^ ((n & 7) << 4));
            bv[nf] = *(const bf16x8*)((const char*)lds_w1 + boff);
        }
#pragma unroll
        for (int mf = 0; mf < 2; ++mf)
#pragma unroll
            for (int nf = 0; nf < 4; ++nf)
                acc1[mf][nf] = __builtin_amdgcn_mfma_f32_16x16x32_bf16(av[mf], bv[nf], acc1[mf][nf], 0, 0, 0);
    }

    __syncthreads();

    // bias1 + ReLU -> X2 (bf16, swizzled) into lds_x
#pragma unroll
    for (int mf = 0; mf < 2; ++mf)
#pragma unroll
        for (int nf = 0; nf < 4; ++nf) {
            int n = wcol * 64 + nf * 16 + l15;
#pragma unroll
            for (int r = 0; r < 4; ++r) {
                int row = wrow * 32 + mf * 16 + l4 * 4 + r;
                float v = fmaxf(acc1[mf][nf][r] + b1g[nf], 0.f);
                int boff = row * 256 + ((2 * n) ^ ((row & 7) << 4));
                *(unsigned short*)((char*)lds_x + boff) = f2bf(v);
            }
        }

    __syncthreads();

    // GEMM2: h2 = X2 @ W2
    f32x4 acc2[2][4];
#pragma unroll
    for (int mf = 0; mf < 2; ++mf)
#pragma unroll
        for (int nf = 0; nf < 4; ++nf) acc2[mf][nf] = (f32x4){0.f, 0.f, 0.f, 0.f};

#pragma unroll
    for (int kc = 0; kc < 4; ++kc) {
        bf16x8 av[2], bv[4];
#pragma unroll
        for (int mf = 0; mf < 2; ++mf) {
            int r = wrow * 32 + mf * 16 + l15;
            int boff = r * 256 + (((kc * 64) + l4 * 16) ^ ((r & 7) << 4));
            av[mf] = *(const bf16x8*)((const char*)lds_x + boff);
        }
#pragma unroll
        for (int nf = 0; nf < 4; ++nf) {
            int n = wcol * 64 + nf * 16 + l15;
            int boff = n * 256 + (((kc * 64) + l4 * 16) ^ ((n & 7) << 4));
            bv[nf] = *(const bf16x8*)((const char*)lds_w2 + boff);
        }
#pragma unroll
        for (int mf = 0; mf < 2; ++mf)
#pragma unroll
            for (int nf = 0; nf < 4; ++nf)
                acc2[mf][nf] = __builtin_amdgcn_mfma_f32_16x16x32_bf16(av[mf], bv[nf], acc2[mf][nf], 0, 0, 0);
    }

    __syncthreads();
    float* cs = (float*)lds_x;
    cs[tid] = 0.f;     // [0..127]=colsum, [128..255]=colsumsq
    __syncthreads();

    // epilogue: bias2, store h2 (in place), column partials
    float psum[4] = {0.f, 0.f, 0.f, 0.f}, psq[4] = {0.f, 0.f, 0.f, 0.f};
#pragma unroll
    for (int mf = 0; mf < 2; ++mf)
#pragma unroll
        for (int nf = 0; nf < 4; ++nf) {
            int n = wcol * 64 + nf * 16 + l15;
#pragma unroll
            for (int r = 0; r < 4; ++r) {
                int row = m0 + wrow * 32 + mf * 16 + l4 * 4 + r;
                float v = acc2[mf][nf][r] + b2g[nf];
                if (row < N_NODES) {
                    hbuf[(size_t)row * HID + n] = v;
                    psum[nf] += v;
                    psq[nf] += v * v;
                }
            }
        }
#pragma unroll
    for (int nf = 0; nf < 4; ++nf) {
        float s = psum[nf], q = psq[nf];
        s += __shfl_xor(s, 16); q += __shfl_xor(q, 16);
        s += __shfl_xor(s, 32); q += __shfl_xor(q, 32);
        if (lane < 16) {
            int n = wcol * 64 + nf * 16 + lane;
            atomicAdd(&cs[n], s);
            atomicAdd(&cs[HID + n], q);
        }
    }
    __syncthreads();
    atomicAdd(&shadow[(bid & 63) * 256 + tid], cs[tid]);
}

// finalize BN scale/shift from shadow partials
__global__ void k_finalize(const float* __restrict__ shadow,
                           const float* __restrict__ gamma,
                           const float* __restrict__ beta,
                           float* __restrict__ sc) {
    int c = threadIdx.x;     // 0..127
    float sum = 0.f, sq = 0.f;
    for (int i = 0; i < 64; ++i) {
        sum += shadow[i * 256 + c];
        sq  += shadow[i * 256 + 128 + c];
    }
    float mean = sum * (1.0f / N_NODES);
    float var  = sq * (1.0f / N_NODES) - mean * mean;
    float r = rsqrtf(var + BN_EPS);
    float scale = gamma[c] * r;
    sc[c]       = scale;
    sc[128 + c] = beta[c] - mean * scale;
}

__global__ __launch_bounds__(256) void k_bn(const float* __restrict__ h2,
                                            const float* __restrict__ sc,
                                            float* __restrict__ out) {
    int t = blockIdx.x * 256 + threadIdx.x;
    int c4 = t & 31;
    float4 scale = ((const float4*)sc)[c4];
    float4 shift = ((const float4*)sc)[32 + c4];
    float4 h = ((const float4*)h2)[t];
    float4 o;
    o.x = h.x * scale.x + shift.x;
    o.y = h.y * scale.y + shift.y;
    o.z = h.z * scale.z + shift.z;
    o.w = h.w * scale.w + shift.w;
    ((float4*)out)[t] = o;
}

extern "C" void kernel_launch(void* const* d_in, const int* in_sizes, int n_in,
                              void* d_out, int out_size, void* d_ws, size_t ws_size,
                              hipStream_t stream) {
    const float* x0 = (const float*)d_in[0];
    const float* x1 = (const float*)d_in[1];
    const int*   ei = (const int*)d_in[2];
    const float* mw = (const float*)d_in[3];
    const float* W1 = (const float*)d_in[4];
    const float* b1 = (const float*)d_in[5];
    const float* W2 = (const float*)d_in[6];
    const float* b2 = (const float*)d_in[7];
    const float* gamma = (const float*)d_in[8];
    const float* beta  = (const float*)d_in[9];

    float* out    = (float*)d_out;
    float* acc    = (float*)d_ws;                         // 12.8M floats (h, then h2)
    float* shadow = acc + (size_t)N_NODES * HID;          // 16384
    float* sc     = shadow + 16384;                       // 256
    unsigned short* W1T = (unsigned short*)(sc + 256);    // 16384 u16
    unsigned short* W2T = W1T + 16384;                    // 16384 u16
    int* head    = (int*)(W2T + 16384);                   // 100,000
    int* nxt     = head + N_NODES;                        // 1,600,000

    size_t needed = (size_t)((char*)(nxt + N_EDGES) - (char*)d_ws);

    int nthread4 = N_NODES * HID / 4;                     // 3,200,000
    k_gate<<<nthread4 / 256, 256, 0, stream>>>(x0, x1, mw, out, shadow, head);
    k_prep<<<64, 256, 0, stream>>>(W1, W2, W1T, W2T);

    if (ws_size >= needed) {
        k_build<<<N_EDGES / 256, 256, 0, stream>>>(ei, head, nxt);
        k_agg<<<N_NODES / 4, 256, 0, stream>>>(out, ei, head, nxt, acc);
    } else {
        hipMemcpyAsync(acc, out, (size_t)N_NODES * HID * sizeof(float),
                       hipMemcpyDeviceToDevice, stream);
        long long total = (long long)N_EDGES * 32;
        k_scatter<<<(int)(total / 256), 256, 0, stream>>>(ei, out, acc);
    }

    // MFMA MLP (in-place h -> h2) + column sums
    k_mlp<<<(N_NODES + BM - 1) / BM, 256, 0, stream>>>(acc, W1T, W2T, b1, b2, shadow);
    k_finalize<<<1, 128, 0, stream>>>(shadow, gamma, beta, sc);
    k_bn<<<nthread4 / 256, 256, 0, stream>>>(acc, sc, out);
}

// Round 5
// 310.734 us; speedup vs baseline: 9.9178x; 1.0891x over previous
//
#include <hip/hip_runtime.h>
#include <math.h>

#define N_NODES 100000
#define N_EDGES 1600000
#define HID 128
#define BN_EPS 1e-5f
#define BM 64

typedef __attribute__((ext_vector_type(8))) short bf16x8;
typedef __attribute__((ext_vector_type(4))) float f32x4;

__device__ inline unsigned short f2bf(float f) {
    unsigned u = __float_as_uint(f);
    unsigned r = u + 0x7FFFu + ((u >> 16) & 1u);   // RNE
    return (unsigned short)(r >> 16);
}
__device__ inline unsigned pk2(float lo, float hi) {
    return (unsigned)f2bf(lo) | ((unsigned)f2bf(hi) << 16);
}
__device__ inline float bflo(unsigned u) { return __uint_as_float(u << 16); }
__device__ inline float bfhi(unsigned u) { return __uint_as_float(u & 0xffff0000u); }

// K1: gate(bf16) = s0*x0 + s1*x1 ; zero shadow ; head = -1
__global__ __launch_bounds__(256) void k_gate(const float* __restrict__ x0,
                                              const float* __restrict__ x1,
                                              const float* __restrict__ mw,
                                              unsigned* __restrict__ gate_u2,  // uint2 view
                                              float* __restrict__ shadow,
                                              int* __restrict__ head) {
    int t = blockIdx.x * 256 + threadIdx.x;            // 4-elem group index, exact grid
    if (blockIdx.x < 64) shadow[t] = 0.0f;
    if (t < N_NODES) head[t] = -1;
    float s0 = 1.0f / (1.0f + expf(-mw[0]));
    float s1 = 1.0f / (1.0f + expf(-mw[1]));
    float4 a = ((const float4*)x0)[t];
    float4 b = ((const float4*)x1)[t];
    uint2 o;
    o.x = pk2(s0 * a.x + s1 * b.x, s0 * a.y + s1 * b.y);
    o.y = pk2(s0 * a.z + s1 * b.z, s0 * a.w + s1 * b.w);
    ((uint2*)gate_u2)[t] = o;
}

// one-time: W1,W2 fp32 [k][n] -> bf16 transposed [n][k]
__global__ __launch_bounds__(256) void k_prep(const float* __restrict__ W1,
                                              const float* __restrict__ W2,
                                              unsigned short* __restrict__ W1T,
                                              unsigned short* __restrict__ W2T) {
    int t = blockIdx.x * 256 + threadIdx.x;            // 16384 threads
    int k = t >> 7, n = t & 127;
    W1T[n * HID + k] = f2bf(W1[t]);
    W2T[n * HID + k] = f2bf(W2[t]);
}

// build per-dst linked list: nxt[e] = old head, head[dst] = e
__global__ __launch_bounds__(256) void k_build(const int* __restrict__ ei,
                                               int* __restrict__ head,
                                               int* __restrict__ nxt) {
    int e = blockIdx.x * 256 + threadIdx.x;            // exact: N_EDGES threads
    int dst = ei[N_EDGES + e];
    nxt[e] = atomicExch(&head[dst], e);
}

// gather-sum via list walk: one wave per node, bf16 rows (4B/lane), fp32 accum
__global__ __launch_bounds__(256) void k_agg(const unsigned* __restrict__ gu,   // gate bf16 as uint
                                             const int* __restrict__ ei,
                                             const int* __restrict__ head,
                                             const int* __restrict__ nxt,
                                             unsigned* __restrict__ hbuf_u) {   // h bf16 as uint
    int node = blockIdx.x * 4 + (threadIdx.x >> 6);    // exact: 25000 blocks
    int lane = threadIdx.x & 63;
    unsigned g = gu[node * 64 + lane];
    float sx = bflo(g), sy = bfhi(g);
    int e = head[node];
    while (e >= 0) {
        int src = ei[e];
        int nx  = nxt[e];
        unsigned v = gu[src * 64 + lane];
        sx += bflo(v);
        sy += bfhi(v);
        e = nx;
    }
    hbuf_u[node * 64 + lane] = pk2(sx, sy);
}

// MFMA MLP: 64-row tile, 4 waves (2x2), wave tile 32x64, K=128 in 4 chunks.
// reads h (bf16), writes h2 (fp32) to h2buf; per-column sums into shadow[64][256].
__global__ __launch_bounds__(256, 2) void k_mlp(const unsigned short* __restrict__ hbuf,
                                                float* __restrict__ h2buf,
                                                const unsigned short* __restrict__ W1T,
                                                const unsigned short* __restrict__ W2T,
                                                const float* __restrict__ b1,
                                                const float* __restrict__ b2,
                                                float* __restrict__ shadow) {
    __shared__ short lds_x[BM * HID];        // 16KB: X, then X2, then colsums
    __shared__ short lds_w1[HID * HID];      // 32KB
    __shared__ short lds_w2[HID * HID];      // 32KB

    const int tid = threadIdx.x;
    const int bid = blockIdx.x;
    const int m0 = bid * BM;

    // stage weights (bf16 W^T [n][k]) with XOR swizzle on 16B chunks
    for (int c = tid; c < 2048; c += 256) {
        int n = c >> 4, k16 = c & 15;
        int4 v1 = ((const int4*)W1T)[c];
        int4 v2 = ((const int4*)W2T)[c];
        int boff = n * 256 + ((k16 * 16) ^ ((n & 7) << 4));
        *(int4*)((char*)lds_w1 + boff) = v1;
        *(int4*)((char*)lds_w2 + boff) = v2;
    }
    // stage X rows (already bf16): straight int4 copy into swizzled layout
    for (int c = tid; c < BM * 16; c += 256) {
        int r = c >> 4, k16 = c & 15;
        int row = m0 + r;
        int4 v = {0, 0, 0, 0};
        if (row < N_NODES)
            v = ((const int4*)(hbuf + (size_t)row * HID))[k16];
        int boff = r * 256 + ((k16 * 16) ^ ((r & 7) << 4));
        *(int4*)((char*)lds_x + boff) = v;
    }

    const int wid = tid >> 6, lane = tid & 63;
    const int wrow = wid >> 1, wcol = wid & 1;
    const int l15 = lane & 15, l4 = lane >> 4;

    float b1g[4], b2g[4];
#pragma unroll
    for (int nf = 0; nf < 4; ++nf) {
        int n = wcol * 64 + nf * 16 + l15;
        b1g[nf] = b1[n];
        b2g[nf] = b2[n];
    }

    __syncthreads();

    // GEMM1: Y = X @ W1
    f32x4 acc1[2][4];
#pragma unroll
    for (int mf = 0; mf < 2; ++mf)
#pragma unroll
        for (int nf = 0; nf < 4; ++nf) acc1[mf][nf] = (f32x4){0.f, 0.f, 0.f, 0.f};

#pragma unroll
    for (int kc = 0; kc < 4; ++kc) {
        bf16x8 av[2], bv[4];
#pragma unroll
        for (int mf = 0; mf < 2; ++mf) {
            int r = wrow * 32 + mf * 16 + l15;
            int boff = r * 256 + (((kc * 64) + l4 * 16) ^ ((r & 7) << 4));
            av[mf] = *(const bf16x8*)((const char*)lds_x + boff);
        }
#pragma unroll
        for (int nf = 0; nf < 4; ++nf) {
            int n = wcol * 64 + nf * 16 + l15;
            int boff = n * 256 + (((kc * 64) + l4 * 16) ^ ((n & 7) << 4));
            bv[nf] = *(const bf16x8*)((const char*)lds_w1 + boff);
        }
#pragma unroll
        for (int mf = 0; mf < 2; ++mf)
#pragma unroll
            for (int nf = 0; nf < 4; ++nf)
                acc1[mf][nf] = __builtin_amdgcn_mfma_f32_16x16x32_bf16(av[mf], bv[nf], acc1[mf][nf], 0, 0, 0);
    }

    __syncthreads();

    // bias1 + ReLU -> X2 (bf16, swizzled) into lds_x
#pragma unroll
    for (int mf = 0; mf < 2; ++mf)
#pragma unroll
        for (int nf = 0; nf < 4; ++nf) {
            int n = wcol * 64 + nf * 16 + l15;
#pragma unroll
            for (int r = 0; r < 4; ++r) {
                int row = wrow * 32 + mf * 16 + l4 * 4 + r;
                float v = fmaxf(acc1[mf][nf][r] + b1g[nf], 0.f);
                int boff = row * 256 + ((2 * n) ^ ((row & 7) << 4));
                *(unsigned short*)((char*)lds_x + boff) = f2bf(v);
            }
        }

    __syncthreads();

    // GEMM2: h2 = X2 @ W2
    f32x4 acc2[2][4];
#pragma unroll
    for (int mf = 0; mf < 2; ++mf)
#pragma unroll
        for (int nf = 0; nf < 4; ++nf) acc2[mf][nf] = (f32x4){0.f, 0.f, 0.f, 0.f};

#pragma unroll
    for (int kc = 0; kc < 4; ++kc) {
        bf16x8 av[2], bv[4];
#pragma unroll
        for (int mf = 0; mf < 2; ++mf) {
            int r = wrow * 32 + mf * 16 + l15;
            int boff = r * 256 + (((kc * 64) + l4 * 16) ^ ((r & 7) << 4));
            av[mf] = *(const bf16x8*)((const char*)lds_x + boff);
        }
#pragma unroll
        for (int nf = 0; nf < 4; ++nf) {
            int n = wcol * 64 + nf * 16 + l15;
            int boff = n * 256 + (((kc * 64) + l4 * 16) ^ ((n & 7) << 4));
            bv[nf] = *(const bf16x8*)((const char*)lds_w2 + boff);
        }
#pragma unroll
        for (int mf = 0; mf < 2; ++mf)
#pragma unroll
            for (int nf = 0; nf < 4; ++nf)
                acc2[mf][nf] = __builtin_amdgcn_mfma_f32_16x16x32_bf16(av[mf], bv[nf], acc2[mf][nf], 0, 0, 0);
    }

    __syncthreads();
    float* cs = (float*)lds_x;
    cs[tid] = 0.f;     // [0..127]=colsum, [128..255]=colsumsq
    __syncthreads();

    // epilogue: bias2, store h2 fp32, column partials
    float psum[4] = {0.f, 0.f, 0.f, 0.f}, psq[4] = {0.f, 0.f, 0.f, 0.f};
#pragma unroll
    for (int mf = 0; mf < 2; ++mf)
#pragma unroll
        for (int nf = 0; nf < 4; ++nf) {
            int n = wcol * 64 + nf * 16 + l15;
#pragma unroll
            for (int r = 0; r < 4; ++r) {
                int row = m0 + wrow * 32 + mf * 16 + l4 * 4 + r;
                float v = acc2[mf][nf][r] + b2g[nf];
                if (row < N_NODES) {
                    h2buf[(size_t)row * HID + n] = v;
                    psum[nf] += v;
                    psq[nf] += v * v;
                }
            }
        }
#pragma unroll
    for (int nf = 0; nf < 4; ++nf) {
        float s = psum[nf], q = psq[nf];
        s += __shfl_xor(s, 16); q += __shfl_xor(q, 16);
        s += __shfl_xor(s, 32); q += __shfl_xor(q, 32);
        if (lane < 16) {
            int n = wcol * 64 + nf * 16 + lane;
            atomicAdd(&cs[n], s);
            atomicAdd(&cs[HID + n], q);
        }
    }
    __syncthreads();
    atomicAdd(&shadow[(bid & 63) * 256 + tid], cs[tid]);
}

// finalize BN scale/shift from shadow partials
__global__ void k_finalize(const float* __restrict__ shadow,
                           const float* __restrict__ gamma,
                           const float* __restrict__ beta,
                           float* __restrict__ sc) {
    int c = threadIdx.x;     // 0..127
    float sum = 0.f, sq = 0.f;
    for (int i = 0; i < 64; ++i) {
        sum += shadow[i * 256 + c];
        sq  += shadow[i * 256 + 128 + c];
    }
    float mean = sum * (1.0f / N_NODES);
    float var  = sq * (1.0f / N_NODES) - mean * mean;
    float r = rsqrtf(var + BN_EPS);
    float scale = gamma[c] * r;
    sc[c]       = scale;
    sc[128 + c] = beta[c] - mean * scale;
}

// in-place BN apply on d_out (reads h2, writes out at same index)
__global__ __launch_bounds__(256) void k_bn(float* __restrict__ buf,
                                            const float* __restrict__ sc) {
    int t = blockIdx.x * 256 + threadIdx.x;
    int c4 = t & 31;
    float4 scale = ((const float4*)sc)[c4];
    float4 shift = ((const float4*)sc)[32 + c4];
    float4 h = ((const float4*)buf)[t];
    float4 o;
    o.x = h.x * scale.x + shift.x;
    o.y = h.y * scale.y + shift.y;
    o.z = h.z * scale.z + shift.z;
    o.w = h.w * scale.w + shift.w;
    ((float4*)buf)[t] = o;
}

extern "C" void kernel_launch(void* const* d_in, const int* in_sizes, int n_in,
                              void* d_out, int out_size, void* d_ws, size_t ws_size,
                              hipStream_t stream) {
    const float* x0 = (const float*)d_in[0];
    const float* x1 = (const float*)d_in[1];
    const int*   ei = (const int*)d_in[2];
    const float* mw = (const float*)d_in[3];
    const float* W1 = (const float*)d_in[4];
    const float* b1 = (const float*)d_in[5];
    const float* W2 = (const float*)d_in[6];
    const float* b2 = (const float*)d_in[7];
    const float* gamma = (const float*)d_in[8];
    const float* beta  = (const float*)d_in[9];

    float* out = (float*)d_out;                            // gate(bf16) -> h2(fp32) -> out

    unsigned short* hbuf = (unsigned short*)d_ws;          // 12.8M bf16 (h)
    float* shadow = (float*)(hbuf + (size_t)N_NODES * HID);// 16384
    float* sc     = shadow + 16384;                        // 256
    unsigned short* W1T = (unsigned short*)(sc + 256);     // 16384 u16
    unsigned short* W2T = W1T + 16384;                     // 16384 u16
    int* head    = (int*)(W2T + 16384);                    // 100,000
    int* nxt     = head + N_NODES;                         // 1,600,000

    int nthread4 = N_NODES * HID / 4;                      // 3,200,000

    k_gate<<<nthread4 / 256, 256, 0, stream>>>(x0, x1, mw, (unsigned*)out, shadow, head);
    k_prep<<<64, 256, 0, stream>>>(W1, W2, W1T, W2T);
    k_build<<<N_EDGES / 256, 256, 0, stream>>>(ei, head, nxt);
    k_agg<<<N_NODES / 4, 256, 0, stream>>>((const unsigned*)out, ei, head, nxt, (unsigned*)hbuf);
    k_mlp<<<(N_NODES + BM - 1) / BM, 256, 0, stream>>>(hbuf, out, W1T, W2T, b1, b2, shadow);
    k_finalize<<<1, 128, 0, stream>>>(shadow, gamma, beta, sc);
    k_bn<<<nthread4 / 256, 256, 0, stream>>>(out, sc);
}

// Round 6
// 284.856 us; speedup vs baseline: 10.8188x; 1.0908x over previous
//
#include <hip/hip_runtime.h>
#include <math.h>

#define N_NODES 100000
#define N_EDGES 1600000
#define HID 128
#define BN_EPS 1e-5f
#define BM 64
#define IPN 8   // chains walked concurrently per wave

typedef __attribute__((ext_vector_type(8))) short bf16x8;
typedef __attribute__((ext_vector_type(4))) float f32x4;

__device__ inline unsigned short f2bf(float f) {
    unsigned u = __float_as_uint(f);
    unsigned r = u + 0x7FFFu + ((u >> 16) & 1u);   // RNE
    return (unsigned short)(r >> 16);
}
__device__ inline unsigned pk2(float lo, float hi) {
    return (unsigned)f2bf(lo) | ((unsigned)f2bf(hi) << 16);
}
__device__ inline float bflo(unsigned u) { return __uint_as_float(u << 16); }
__device__ inline float bfhi(unsigned u) { return __uint_as_float(u & 0xffff0000u); }

// K1: gate(bf16) = s0*x0 + s1*x1 ; zero shadow ; head = -1
__global__ __launch_bounds__(256) void k_gate(const float* __restrict__ x0,
                                              const float* __restrict__ x1,
                                              const float* __restrict__ mw,
                                              unsigned* __restrict__ gate_u2,  // uint2 view
                                              float* __restrict__ shadow,
                                              int* __restrict__ head) {
    int t = blockIdx.x * 256 + threadIdx.x;            // 4-elem group index, exact grid
    if (blockIdx.x < 64) shadow[t] = 0.0f;
    if (t < N_NODES) head[t] = -1;
    float s0 = 1.0f / (1.0f + expf(-mw[0]));
    float s1 = 1.0f / (1.0f + expf(-mw[1]));
    float4 a = ((const float4*)x0)[t];
    float4 b = ((const float4*)x1)[t];
    uint2 o;
    o.x = pk2(s0 * a.x + s1 * b.x, s0 * a.y + s1 * b.y);
    o.y = pk2(s0 * a.z + s1 * b.z, s0 * a.w + s1 * b.w);
    ((uint2*)gate_u2)[t] = o;
}

// one-time: W1,W2 fp32 [k][n] -> bf16 transposed [n][k]
__global__ __launch_bounds__(256) void k_prep(const float* __restrict__ W1,
                                              const float* __restrict__ W2,
                                              unsigned short* __restrict__ W1T,
                                              unsigned short* __restrict__ W2T) {
    int t = blockIdx.x * 256 + threadIdx.x;            // 16384 threads
    int k = t >> 7, n = t & 127;
    W1T[n * HID + k] = f2bf(W1[t]);
    W2T[n * HID + k] = f2bf(W2[t]);
}

// build per-dst linked list: nxt[e] = old head, head[dst] = e
__global__ __launch_bounds__(256) void k_build(const int* __restrict__ ei,
                                               int* __restrict__ head,
                                               int* __restrict__ nxt) {
    int e = blockIdx.x * 256 + threadIdx.x;            // exact: N_EDGES threads
    int dst = ei[N_EDGES + e];
    nxt[e] = atomicExch(&head[dst], e);
}

// gather-sum via 8-way concurrent list walk: one wave per 8 nodes
__global__ __launch_bounds__(256) void k_agg(const unsigned* __restrict__ gu,   // gate bf16 as uint
                                             const int* __restrict__ ei,
                                             const int* __restrict__ head,
                                             const int* __restrict__ nxt,
                                             unsigned* __restrict__ hbuf_u) {   // h bf16 as uint
    int wid = threadIdx.x >> 6, lane = threadIdx.x & 63;
    int nbase = (blockIdx.x * 4 + wid) * IPN;          // exact: 3125 blocks
    float sx[IPN], sy[IPN];
    int e[IPN];
#pragma unroll
    for (int i = 0; i < IPN; ++i) {
        unsigned g = gu[(nbase + i) * 64 + lane];
        sx[i] = bflo(g); sy[i] = bfhi(g);
        e[i] = head[nbase + i];
    }
    bool any = false;
#pragma unroll
    for (int i = 0; i < IPN; ++i) any |= (e[i] >= 0);
    while (any) {
        int srcv[IPN], nx[IPN];
        // issue phase: 8 independent chain loads in flight
#pragma unroll
        for (int i = 0; i < IPN; ++i) if (e[i] >= 0) {
            srcv[i] = ei[e[i]];
            nx[i]   = nxt[e[i]];
        }
        // consume phase: 8 independent row gathers in flight
#pragma unroll
        for (int i = 0; i < IPN; ++i) if (e[i] >= 0) {
            unsigned v = gu[srcv[i] * 64 + lane];
            sx[i] += bflo(v);
            sy[i] += bfhi(v);
            e[i] = nx[i];
        }
        any = false;
#pragma unroll
        for (int i = 0; i < IPN; ++i) any |= (e[i] >= 0);
    }
#pragma unroll
    for (int i = 0; i < IPN; ++i)
        hbuf_u[(nbase + i) * 64 + lane] = pk2(sx[i], sy[i]);
}

// MFMA MLP: 64-row tile, 4 waves (2x2), wave tile 32x64, K=128 in 4 chunks.
// reads h (bf16), writes h2 (fp32) to h2buf; per-column sums into shadow[64][256].
__global__ __launch_bounds__(256, 2) void k_mlp(const unsigned short* __restrict__ hbuf,
                                                float* __restrict__ h2buf,
                                                const unsigned short* __restrict__ W1T,
                                                const unsigned short* __restrict__ W2T,
                                                const float* __restrict__ b1,
                                                const float* __restrict__ b2,
                                                float* __restrict__ shadow) {
    __shared__ short lds_x[BM * HID];        // 16KB: X, then X2, then colsums
    __shared__ short lds_w1[HID * HID];      // 32KB
    __shared__ short lds_w2[HID * HID];      // 32KB

    const int tid = threadIdx.x;
    const int bid = blockIdx.x;
    const int m0 = bid * BM;

    // stage weights (bf16 W^T [n][k]) with XOR swizzle on 16B chunks
    for (int c = tid; c < 2048; c += 256) {
        int n = c >> 4, k16 = c & 15;
        int4 v1 = ((const int4*)W1T)[c];
        int4 v2 = ((const int4*)W2T)[c];
        int boff = n * 256 + ((k16 * 16) ^ ((n & 7) << 4));
        *(int4*)((char*)lds_w1 + boff) = v1;
        *(int4*)((char*)lds_w2 + boff) = v2;
    }
    // stage X rows (already bf16): straight int4 copy into swizzled layout
    for (int c = tid; c < BM * 16; c += 256) {
        int r = c >> 4, k16 = c & 15;
        int row = m0 + r;
        int4 v = {0, 0, 0, 0};
        if (row < N_NODES)
            v = ((const int4*)(hbuf + (size_t)row * HID))[k16];
        int boff = r * 256 + ((k16 * 16) ^ ((r & 7) << 4));
        *(int4*)((char*)lds_x + boff) = v;
    }

    const int wid = tid >> 6, lane = tid & 63;
    const int wrow = wid >> 1, wcol = wid & 1;
    const int l15 = lane & 15, l4 = lane >> 4;

    float b1g[4], b2g[4];
#pragma unroll
    for (int nf = 0; nf < 4; ++nf) {
        int n = wcol * 64 + nf * 16 + l15;
        b1g[nf] = b1[n];
        b2g[nf] = b2[n];
    }

    __syncthreads();

    // GEMM1: Y = X @ W1
    f32x4 acc1[2][4];
#pragma unroll
    for (int mf = 0; mf < 2; ++mf)
#pragma unroll
        for (int nf = 0; nf < 4; ++nf) acc1[mf][nf] = (f32x4){0.f, 0.f, 0.f, 0.f};

#pragma unroll
    for (int kc = 0; kc < 4; ++kc) {
        bf16x8 av[2], bv[4];
#pragma unroll
        for (int mf = 0; mf < 2; ++mf) {
            int r = wrow * 32 + mf * 16 + l15;
            int boff = r * 256 + (((kc * 64) + l4 * 16) ^ ((r & 7) << 4));
            av[mf] = *(const bf16x8*)((const char*)lds_x + boff);
        }
#pragma unroll
        for (int nf = 0; nf < 4; ++nf) {
            int n = wcol * 64 + nf * 16 + l15;
            int boff = n * 256 + (((kc * 64) + l4 * 16) ^ ((n & 7) << 4));
            bv[nf] = *(const bf16x8*)((const char*)lds_w1 + boff);
        }
#pragma unroll
        for (int mf = 0; mf < 2; ++mf)
#pragma unroll
            for (int nf = 0; nf < 4; ++nf)
                acc1[mf][nf] = __builtin_amdgcn_mfma_f32_16x16x32_bf16(av[mf], bv[nf], acc1[mf][nf], 0, 0, 0);
    }

    __syncthreads();

    // bias1 + ReLU -> X2 (bf16, swizzled) into lds_x
#pragma unroll
    for (int mf = 0; mf < 2; ++mf)
#pragma unroll
        for (int nf = 0; nf < 4; ++nf) {
            int n = wcol * 64 + nf * 16 + l15;
#pragma unroll
            for (int r = 0; r < 4; ++r) {
                int row = wrow * 32 + mf * 16 + l4 * 4 + r;
                float v = fmaxf(acc1[mf][nf][r] + b1g[nf], 0.f);
                int boff = row * 256 + ((2 * n) ^ ((row & 7) << 4));
                *(unsigned short*)((char*)lds_x + boff) = f2bf(v);
            }
        }

    __syncthreads();

    // GEMM2: h2 = X2 @ W2
    f32x4 acc2[2][4];
#pragma unroll
    for (int mf = 0; mf < 2; ++mf)
#pragma unroll
        for (int nf = 0; nf < 4; ++nf) acc2[mf][nf] = (f32x4){0.f, 0.f, 0.f, 0.f};

#pragma unroll
    for (int kc = 0; kc < 4; ++kc) {
        bf16x8 av[2], bv[4];
#pragma unroll
        for (int mf = 0; mf < 2; ++mf) {
            int r = wrow * 32 + mf * 16 + l15;
            int boff = r * 256 + (((kc * 64) + l4 * 16) ^ ((r & 7) << 4));
            av[mf] = *(const bf16x8*)((const char*)lds_x + boff);
        }
#pragma unroll
        for (int nf = 0; nf < 4; ++nf) {
            int n = wcol * 64 + nf * 16 + l15;
            int boff = n * 256 + (((kc * 64) + l4 * 16) ^ ((n & 7) << 4));
            bv[nf] = *(const bf16x8*)((const char*)lds_w2 + boff);
        }
#pragma unroll
        for (int mf = 0; mf < 2; ++mf)
#pragma unroll
            for (int nf = 0; nf < 4; ++nf)
                acc2[mf][nf] = __builtin_amdgcn_mfma_f32_16x16x32_bf16(av[mf], bv[nf], acc2[mf][nf], 0, 0, 0);
    }

    __syncthreads();
    float* cs = (float*)lds_x;
    cs[tid] = 0.f;     // [0..127]=colsum, [128..255]=colsumsq
    __syncthreads();

    // epilogue: bias2, store h2 fp32, column partials
    float psum[4] = {0.f, 0.f, 0.f, 0.f}, psq[4] = {0.f, 0.f, 0.f, 0.f};
#pragma unroll
    for (int mf = 0; mf < 2; ++mf)
#pragma unroll
        for (int nf = 0; nf < 4; ++nf) {
            int n = wcol * 64 + nf * 16 + l15;
#pragma unroll
            for (int r = 0; r < 4; ++r) {
                int row = m0 + wrow * 32 + mf * 16 + l4 * 4 + r;
                float v = acc2[mf][nf][r] + b2g[nf];
                if (row < N_NODES) {
                    h2buf[(size_t)row * HID + n] = v;
                    psum[nf] += v;
                    psq[nf] += v * v;
                }
            }
        }
#pragma unroll
    for (int nf = 0; nf < 4; ++nf) {
        float s = psum[nf], q = psq[nf];
        s += __shfl_xor(s, 16); q += __shfl_xor(q, 16);
        s += __shfl_xor(s, 32); q += __shfl_xor(q, 32);
        if (lane < 16) {
            int n = wcol * 64 + nf * 16 + lane;
            atomicAdd(&cs[n], s);
            atomicAdd(&cs[HID + n], q);
        }
    }
    __syncthreads();
    atomicAdd(&shadow[(bid & 63) * 256 + tid], cs[tid]);
}

// finalize BN scale/shift from shadow partials
__global__ void k_finalize(const float* __restrict__ shadow,
                           const float* __restrict__ gamma,
                           const float* __restrict__ beta,
                           float* __restrict__ sc) {
    int c = threadIdx.x;     // 0..127
    float sum = 0.f, sq = 0.f;
    for (int i = 0; i < 64; ++i) {
        sum += shadow[i * 256 + c];
        sq  += shadow[i * 256 + 128 + c];
    }
    float mean = sum * (1.0f / N_NODES);
    float var  = sq * (1.0f / N_NODES) - mean * mean;
    float r = rsqrtf(var + BN_EPS);
    float scale = gamma[c] * r;
    sc[c]       = scale;
    sc[128 + c] = beta[c] - mean * scale;
}

// in-place BN apply on d_out (reads h2, writes out at same index)
__global__ __launch_bounds__(256) void k_bn(float* __restrict__ buf,
                                            const float* __restrict__ sc) {
    int t = blockIdx.x * 256 + threadIdx.x;
    int c4 = t & 31;
    float4 scale = ((const float4*)sc)[c4];
    float4 shift = ((const float4*)sc)[32 + c4];
    float4 h = ((const float4*)buf)[t];
    float4 o;
    o.x = h.x * scale.x + shift.x;
    o.y = h.y * scale.y + shift.y;
    o.z = h.z * scale.z + shift.z;
    o.w = h.w * scale.w + shift.w;
    ((float4*)buf)[t] = o;
}

extern "C" void kernel_launch(void* const* d_in, const int* in_sizes, int n_in,
                              void* d_out, int out_size, void* d_ws, size_t ws_size,
                              hipStream_t stream) {
    const float* x0 = (const float*)d_in[0];
    const float* x1 = (const float*)d_in[1];
    const int*   ei = (const int*)d_in[2];
    const float* mw = (const float*)d_in[3];
    const float* W1 = (const float*)d_in[4];
    const float* b1 = (const float*)d_in[5];
    const float* W2 = (const float*)d_in[6];
    const float* b2 = (const float*)d_in[7];
    const float* gamma = (const float*)d_in[8];
    const float* beta  = (const float*)d_in[9];

    float* out = (float*)d_out;                            // gate(bf16) -> h2(fp32) -> out

    unsigned short* hbuf = (unsigned short*)d_ws;          // 12.8M bf16 (h)
    float* shadow = (float*)(hbuf + (size_t)N_NODES * HID);// 16384
    float* sc     = shadow + 16384;                        // 256
    unsigned short* W1T = (unsigned short*)(sc + 256);     // 16384 u16
    unsigned short* W2T = W1T + 16384;                     // 16384 u16
    int* head    = (int*)(W2T + 16384);                    // 100,000
    int* nxt     = head + N_NODES;                         // 1,600,000

    int nthread4 = N_NODES * HID / 4;                      // 3,200,000

    k_gate<<<nthread4 / 256, 256, 0, stream>>>(x0, x1, mw, (unsigned*)out, shadow, head);
    k_prep<<<64, 256, 0, stream>>>(W1, W2, W1T, W2T);
    k_build<<<N_EDGES / 256, 256, 0, stream>>>(ei, head, nxt);
    k_agg<<<N_NODES / (4 * IPN), 256, 0, stream>>>((const unsigned*)out, ei, head, nxt, (unsigned*)hbuf);
    k_mlp<<<(N_NODES + BM - 1) / BM, 256, 0, stream>>>(hbuf, out, W1T, W2T, b1, b2, shadow);
    k_finalize<<<1, 128, 0, stream>>>(shadow, gamma, beta, sc);
    k_bn<<<nthread4 / 256, 256, 0, stream>>>(out, sc);
}